// Round 1
// baseline (2160.606 us; speedup 1.0000x reference)
//
#include <hip/hip_runtime.h>
#include <hip/hip_bf16.h>
#include <stdint.h>

// Problem constants
#define NUQ 16000
#define NMQ 8000
#define EQ  64
#define LQ  3
#define BQ  100000

// GEMM tiling: M-tile 64, K-split 5
#define SPLIT 5
#define MOVIE_BLOCKS (125 * SPLIT)   // 625
#define USER_BLOCKS  (250 * SPLIT)   // 1250
#define GEMM_BLOCKS  (MOVIE_BLOCKS + USER_BLOCKS)  // 1875

typedef short short8 __attribute__((ext_vector_type(8)));
typedef float f32x4  __attribute__((ext_vector_type(4)));
typedef unsigned short ushort_t;

static __device__ __forceinline__ unsigned int bf16_bits(float f) {
    unsigned int u = __float_as_uint(f);
    return (u + 0x7FFFu + ((u >> 16) & 1u)) >> 16;   // RTNE
}
static __device__ __forceinline__ unsigned int pk_bf16(float a, float b) {
    return (bf16_bits(a) & 0xFFFFu) | (bf16_bits(b) << 16);
}

// ---------------------------------------------------------------------------
// prep: transpose-convert embeddings fp32 [K][64] -> bf16 [64][K]
// blocks 0..249: user (K=NU), 250..374: movie (K=NM)
// ---------------------------------------------------------------------------
__global__ __launch_bounds__(256) void prep_kernel(
    const float* __restrict__ uemb, const float* __restrict__ memb,
    ushort_t* __restrict__ uT, ushort_t* __restrict__ mT)
{
    __shared__ float xs[64 * 65];
    int bid = blockIdx.x, t = threadIdx.x;
    bool mside = bid >= 250;
    int k0 = (mside ? (bid - 250) : bid) * 64;
    int ld = mside ? NMQ : NUQ;
    const float* src = mside ? memb : uemb;
    ushort_t* dst = mside ? mT : uT;

    for (int j = 0; j < 16; j++) {
        int idx = j * 256 + t;
        int r = idx >> 6, e = idx & 63;
        xs[r * 65 + e] = src[(size_t)(k0 + r) * 64 + e];
    }
    __syncthreads();
    for (int j = 0; j < 16; j++) {
        int idx = j * 256 + t;
        int e = idx >> 6, rr = idx & 63;
        dst[(size_t)e * ld + k0 + rr] = (ushort_t)bf16_bits(xs[rr * 65 + e]);
    }
}

// ---------------------------------------------------------------------------
// Big GEMM: tmp = adj @ emb   (A fp32/bf16 [M][K], B^T bf16 [64][K])
// MODE 0: read fp32 adj. MODE 1: read fp32, write bf16 copy. MODE 2: read bf16.
// blocks [0,625): movie side, [625,1875): user side. Output: 5 partial slices.
//
// v2: LDS-free, barrier-free streaming GEMM. Each wave owns 16 output rows
// and loads its MFMA A/B fragments DIRECTLY from global memory:
//   A[row][k]: row = M0+wv*16+(lane&15), k = kk+(lane>>4)*8 .. +8  (16B load)
//   B^T[col][k]: col = nb*16+(lane&15), same k                      (16B load)
// Lanes l,l+16,l+32,l+48 cover a contiguous 64B of each row; consecutive
// k-steps consume the other half of each 128B line (L2-held), so HBM traffic
// stays at unique bytes. B^T (<=3 MB) is L2-resident per XCD. No barriers ->
// loads from many independent k-steps stay in flight (the old version drained
// vmcnt(0) at __syncthreads every 64-K step, capping BW at 1.4 TB/s).
// ---------------------------------------------------------------------------
template <int MODE>
__global__ __launch_bounds__(256) void gemm_kernel(
    const float* __restrict__ adjU, const float* __restrict__ adjM,
    ushort_t* __restrict__ adjUb, ushort_t* __restrict__ adjMb,
    const ushort_t* __restrict__ mT, const ushort_t* __restrict__ uT,
    float* __restrict__ tmp_u, float* __restrict__ tmp_m)
{
    int bid = blockIdx.x, t = threadIdx.x;
    bool movie = bid < MOVIE_BLOCKS;
    int tt = movie ? bid : bid - MOVIE_BLOCKS;
    int mt = tt / SPLIT, ch = tt - mt * SPLIT;
    int M0 = mt * 64;
    int ldK = movie ? NUQ : NMQ;
    int KC  = movie ? (NUQ / SPLIT) : (NMQ / SPLIT);   // 3200 / 1600
    int K0  = ch * KC;
    const float* A = movie ? adjM : adjU;
    ushort_t* Ab = movie ? adjMb : adjUb;
    const ushort_t* BT = movie ? uT : mT;
    float* outp = movie ? (tmp_m + ((size_t)ch * NMQ + M0) * 64)
                        : (tmp_u + ((size_t)ch * NUQ + M0) * 64);

    int lane = t & 63, wv = t >> 6;
    int mrow = lane & 15, q = lane >> 4;       // frag row/col = lane&15, k-quad = lane>>4
    int arow = M0 + wv * 16 + mrow;

    // per-lane fragment base pointers (element offsets; all 16B-aligned)
    const ushort_t* aB = Ab ? (Ab + (size_t)arow * ldK + K0 + q * 8) : nullptr;
    ushort_t*       aW = Ab ? (Ab + (size_t)arow * ldK + K0 + q * 8) : nullptr;
    const float*    aF = A + (size_t)arow * ldK + K0 + q * 8;
    const ushort_t* b0 = BT + (size_t)(0 * 16 + mrow) * ldK + K0 + q * 8;
    const ushort_t* b1 = BT + (size_t)(1 * 16 + mrow) * ldK + K0 + q * 8;
    const ushort_t* b2 = BT + (size_t)(2 * 16 + mrow) * ldK + K0 + q * 8;
    const ushort_t* b3 = BT + (size_t)(3 * 16 + mrow) * ldK + K0 + q * 8;

    f32x4 acc[4];
#pragma unroll
    for (int nb = 0; nb < 4; nb++) acc[nb] = (f32x4){0.f, 0.f, 0.f, 0.f};

#pragma unroll 2
    for (int kk = 0; kk < KC; kk += 32) {
        short8 a;
        if (MODE == 2) {
            a = *(const short8*)(aB + kk);
        } else {
            float4 f0 = *(const float4*)(aF + kk);
            float4 f1 = *(const float4*)(aF + kk + 4);
            uint4 qv;
            qv.x = pk_bf16(f0.x, f0.y); qv.y = pk_bf16(f0.z, f0.w);
            qv.z = pk_bf16(f1.x, f1.y); qv.w = pk_bf16(f1.z, f1.w);
            a = *(const short8*)&qv;
            if (MODE == 1) *(uint4*)(aW + kk) = qv;
        }
        short8 vb0 = *(const short8*)(b0 + kk);
        short8 vb1 = *(const short8*)(b1 + kk);
        short8 vb2 = *(const short8*)(b2 + kk);
        short8 vb3 = *(const short8*)(b3 + kk);
        acc[0] = __builtin_amdgcn_mfma_f32_16x16x32_bf16(a, vb0, acc[0], 0, 0, 0);
        acc[1] = __builtin_amdgcn_mfma_f32_16x16x32_bf16(a, vb1, acc[1], 0, 0, 0);
        acc[2] = __builtin_amdgcn_mfma_f32_16x16x32_bf16(a, vb2, acc[2], 0, 0, 0);
        acc[3] = __builtin_amdgcn_mfma_f32_16x16x32_bf16(a, vb3, acc[3], 0, 0, 0);
    }

    // epilogue: C/D layout col=lane&15, row=quad*4+reg  [m89-verified]
    int R0 = wv * 16;
#pragma unroll
    for (int nb = 0; nb < 4; nb++)
#pragma unroll
        for (int r = 0; r < 4; r++)
            outp[(size_t)(R0 + q * 4 + r) * 64 + nb * 16 + mrow] = acc[nb][r];
}

// ---------------------------------------------------------------------------
// transform: x = sum(5 partials) + prev ; y = lrelu(x @ W.T + 2b)
// writes fp32 table + bf16 transposed table (next GEMM's B^T)
// blocks 0..249: user rows, 250..374: movie rows
// ---------------------------------------------------------------------------
__global__ __launch_bounds__(256) void transform_kernel(
    const float* __restrict__ tmp_u, const float* __restrict__ tmp_m,
    const float* __restrict__ prev_u, const float* __restrict__ prev_m,
    const float* __restrict__ Wu, const float* __restrict__ bu,
    const float* __restrict__ Wm, const float* __restrict__ bm,
    float* __restrict__ out_u, float* __restrict__ out_m,
    ushort_t* __restrict__ uT, ushort_t* __restrict__ mT)
{
    __shared__ float xs[64 * 65];
    __shared__ float Ws[64 * 65];
    __shared__ float ys[64 * 65];
    int bid = blockIdx.x, t = threadIdx.x;
    bool mside = bid >= 250;
    int row0 = (mside ? (bid - 250) : bid) * 64;
    int Nrows = mside ? NMQ : NUQ;
    const float* tmp  = mside ? tmp_m : tmp_u;
    const float* prev = mside ? prev_m : prev_u;
    const float* W    = mside ? Wm : Wu;
    const float* bias = mside ? bm : bu;
    float* outp   = mside ? out_m : out_u;
    ushort_t* outT = mside ? mT : uT;

    for (int j = 0; j < 16; j++) {
        int idx = j * 256 + t;
        int r = idx >> 6, e = idx & 63;
        size_t g = (size_t)(row0 + r) * 64 + e;
        float v = prev[g];
#pragma unroll
        for (int s = 0; s < SPLIT; s++) v += tmp[(size_t)s * Nrows * 64 + g];
        xs[r * 65 + e] = v;
        Ws[r * 65 + e] = W[idx];    // W[e'][e], e'=r
    }
    __syncthreads();

    int ep = t & 63, rb = t >> 6;
    float acc[16];
    float b2 = 2.0f * bias[ep];
#pragma unroll
    for (int j = 0; j < 16; j++) acc[j] = b2;
    for (int e = 0; e < 64; e++) {
        float w = Ws[ep * 65 + e];
#pragma unroll
        for (int j = 0; j < 16; j++) acc[j] += xs[(j * 4 + rb) * 65 + e] * w;
    }
#pragma unroll
    for (int j = 0; j < 16; j++) {
        float v = acc[j];
        v = v > 0.f ? v : 0.01f * v;        // leaky_relu 0.01
        ys[(j * 4 + rb) * 65 + ep] = v;
    }
    __syncthreads();

    for (int j = 0; j < 16; j++) {
        int idx = j * 256 + t;
        int r = idx >> 6, e = idx & 63;
        outp[(size_t)(row0 + r) * 64 + e] = ys[r * 65 + e];
        // transposed bf16 write: e2 = idx>>6 is the emb dim, rr = idx&63 the row
        int e2 = r, rr = e;
        outT[(size_t)e2 * Nrows + row0 + rr] = (ushort_t)bf16_bits(ys[rr * 65 + e2]);
    }
}

// ---------------------------------------------------------------------------
// gather: out[b] = sum_l sum_e u_l[uid[b]][e]*m_l[mid[b]][e]*Wo[l*64+e] + bo
// one wave per sample
// ---------------------------------------------------------------------------
__global__ __launch_bounds__(256) void gather_kernel(
    const float* __restrict__ u0, const float* __restrict__ u1,
    const float* __restrict__ u2, const float* __restrict__ u3,
    const float* __restrict__ m0, const float* __restrict__ m1,
    const float* __restrict__ m2, const float* __restrict__ m3,
    const float* __restrict__ Wo, const float* __restrict__ bo,
    const int* __restrict__ uid, const int* __restrict__ mid,
    float* __restrict__ out)
{
    int t = threadIdx.x;
    int lane = t & 63, wv = t >> 6;
    int b = blockIdx.x * 4 + wv;            // grid = 25000 -> exact B
    size_t ui = (size_t)uid[b] * 64 + lane;
    size_t mi = (size_t)mid[b] * 64 + lane;
    float acc = u0[ui] * m0[mi] * Wo[lane]
              + u1[ui] * m1[mi] * Wo[64 + lane]
              + u2[ui] * m2[mi] * Wo[128 + lane]
              + u3[ui] * m3[mi] * Wo[192 + lane];
#pragma unroll
    for (int off = 32; off >= 1; off >>= 1) acc += __shfl_xor(acc, off, 64);
    if (lane == 0) out[b] = acc + bo[0];
}

// ---------------------------------------------------------------------------
extern "C" void kernel_launch(void* const* d_in, const int* in_sizes, int n_in,
                              void* d_out, int out_size, void* d_ws, size_t ws_size,
                              hipStream_t stream)
{
    const float* adjU = (const float*)d_in[0];
    const float* adjM = (const float*)d_in[1];
    const float* uemb = (const float*)d_in[2];
    const float* memb = (const float*)d_in[3];
    const float* Wu   = (const float*)d_in[4];
    const float* bu   = (const float*)d_in[5];
    const float* Wm   = (const float*)d_in[6];
    const float* bm   = (const float*)d_in[7];
    const float* Wo   = (const float*)d_in[8];
    const float* bo   = (const float*)d_in[9];
    const int* uid    = (const int*)d_in[10];
    const int* mid    = (const int*)d_in[11];
    float* out = (float*)d_out;

    char* ws = (char*)d_ws;
    size_t off = 0;
    auto alloc = [&](size_t bytes) -> void* {
        void* p = ws + off;
        off += (bytes + 255) & ~(size_t)255;
        return p;
    };
    float* u_ws = (float*)alloc((size_t)3 * NUQ * 64 * 4);   // u1,u2,u3
    float* m_ws = (float*)alloc((size_t)3 * NMQ * 64 * 4);   // m1,m2,m3
    ushort_t* uT = (ushort_t*)alloc((size_t)64 * NUQ * 2);   // current layer u^T bf16
    ushort_t* mT = (ushort_t*)alloc((size_t)64 * NMQ * 2);
    float* tmp_u = (float*)alloc((size_t)SPLIT * NUQ * 64 * 4);
    float* tmp_m = (float*)alloc((size_t)SPLIT * NMQ * 64 * 4);
    ushort_t* adjUb = (ushort_t*)alloc((size_t)NUQ * NMQ * 2);
    ushort_t* adjMb = (ushort_t*)alloc((size_t)NMQ * NUQ * 2);
    bool compress = (ws_size >= off);
    if (!compress) { adjUb = nullptr; adjMb = nullptr; }

    prep_kernel<<<375, 256, 0, stream>>>(uemb, memb, uT, mT);

    for (int l = 0; l < LQ; l++) {
        if (compress) {
            if (l == 0)
                gemm_kernel<1><<<GEMM_BLOCKS, 256, 0, stream>>>(adjU, adjM, adjUb, adjMb, mT, uT, tmp_u, tmp_m);
            else
                gemm_kernel<2><<<GEMM_BLOCKS, 256, 0, stream>>>(adjU, adjM, adjUb, adjMb, mT, uT, tmp_u, tmp_m);
        } else {
            gemm_kernel<0><<<GEMM_BLOCKS, 256, 0, stream>>>(adjU, adjM, adjUb, adjMb, mT, uT, tmp_u, tmp_m);
        }
        const float* pu = (l == 0) ? uemb : (u_ws + (size_t)(l - 1) * NUQ * 64);
        const float* pm = (l == 0) ? memb : (m_ws + (size_t)(l - 1) * NMQ * 64);
        transform_kernel<<<375, 256, 0, stream>>>(
            tmp_u, tmp_m, pu, pm,
            Wu + (size_t)l * 64 * 64, bu + (size_t)l * 64,
            Wm + (size_t)l * 64 * 64, bm + (size_t)l * 64,
            u_ws + (size_t)l * NUQ * 64, m_ws + (size_t)l * NMQ * 64,
            uT, mT);
    }

    gather_kernel<<<BQ / 4, 256, 0, stream>>>(
        uemb, u_ws, u_ws + (size_t)NUQ * 64, u_ws + (size_t)2 * NUQ * 64,
        memb, m_ws, m_ws + (size_t)NMQ * 64, m_ws + (size_t)2 * NMQ * 64,
        Wo, bo, uid, mid, out);
}

// Round 2
// 1512.475 us; speedup vs baseline: 1.4285x; 1.4285x over previous
//
#include <hip/hip_runtime.h>
#include <hip/hip_bf16.h>
#include <stdint.h>

// Problem constants
#define NUQ 16000
#define NMQ 8000
#define EQ  64
#define LQ  3
#define BQ  100000

// GEMM tiling: M-tile 64, BK=64, K-split 5
#define SPLIT 5
#define MOVIE_BLOCKS (125 * SPLIT)   // 625
#define USER_BLOCKS  (250 * SPLIT)   // 1250
#define GEMM_BLOCKS  (MOVIE_BLOCKS + USER_BLOCKS)  // 1875

typedef short short8 __attribute__((ext_vector_type(8)));
typedef float f32x4  __attribute__((ext_vector_type(4)));
typedef unsigned short ushort_t;

static __device__ __forceinline__ unsigned int bf16_bits(float f) {
    unsigned int u = __float_as_uint(f);
    return (u + 0x7FFFu + ((u >> 16) & 1u)) >> 16;   // RTNE
}
static __device__ __forceinline__ unsigned int pk_bf16(float a, float b) {
    return (bf16_bits(a) & 0xFFFFu) | (bf16_bits(b) << 16);
}

// async global->LDS, 16 B per lane; LDS dest = uniform base + lane*16
static __device__ __forceinline__ void glds16(const ushort_t* g, ushort_t* l) {
    __builtin_amdgcn_global_load_lds(
        (const __attribute__((address_space(1))) void*)g,
        (__attribute__((address_space(3))) void*)l, 16, 0, 0);
}

// ---------------------------------------------------------------------------
// prep: transpose-convert embeddings fp32 [K][64] -> bf16 [64][K]
// blocks 0..249: user (K=NU), 250..374: movie (K=NM)
// ---------------------------------------------------------------------------
__global__ __launch_bounds__(256) void prep_kernel(
    const float* __restrict__ uemb, const float* __restrict__ memb,
    ushort_t* __restrict__ uT, ushort_t* __restrict__ mT)
{
    __shared__ float xs[64 * 65];
    int bid = blockIdx.x, t = threadIdx.x;
    bool mside = bid >= 250;
    int k0 = (mside ? (bid - 250) : bid) * 64;
    int ld = mside ? NMQ : NUQ;
    const float* src = mside ? memb : uemb;
    ushort_t* dst = mside ? mT : uT;

    for (int j = 0; j < 16; j++) {
        int idx = j * 256 + t;
        int r = idx >> 6, e = idx & 63;
        xs[r * 65 + e] = src[(size_t)(k0 + r) * 64 + e];
    }
    __syncthreads();
    for (int j = 0; j < 16; j++) {
        int idx = j * 256 + t;
        int e = idx >> 6, rr = idx & 63;
        dst[(size_t)e * ld + k0 + rr] = (ushort_t)bf16_bits(xs[rr * 65 + e]);
    }
}

// ---------------------------------------------------------------------------
// convert: fp32 adjacency -> bf16 (RTNE), pure stream
// ---------------------------------------------------------------------------
__global__ __launch_bounds__(256) void convert_kernel(
    const float* __restrict__ src, ushort_t* __restrict__ dst, long n)
{
    long i = (long)blockIdx.x * 256 + threadIdx.x;
    long stride = (long)gridDim.x * 256;
    for (; i * 8 < n; i += stride) {
        float4 f0 = *(const float4*)(src + i * 8);
        float4 f1 = *(const float4*)(src + i * 8 + 4);
        uint4 q;
        q.x = pk_bf16(f0.x, f0.y); q.y = pk_bf16(f0.z, f0.w);
        q.z = pk_bf16(f1.x, f1.y); q.w = pk_bf16(f1.z, f1.w);
        *(uint4*)(dst + i * 8) = q;
    }
}

// ---------------------------------------------------------------------------
// Streaming GEMM (bf16 A): tmp = adj_bf16 @ emb   via global_load_lds w=16,
// double-buffered LDS, counted vmcnt (T3/T4 minimal recipe).
//
// LDS tile layout: linear [64 rows][64 bf16] with chunk-XOR swizzle:
//   slot(row, c) holds global chunk c ^ (row&7)   (chunk = 16B = 8 bf16)
// Staging pre-applies the inverse swizzle on the per-lane GLOBAL address
// (global_load_lds writes linearly: dest = base + lane*16) [rule 21].
// ds_read side XORs the same term -> even 8-lanes-per-bank-quad spread.
//
// Per wave per 64-K tile: 4 glds (A 2 + B 2, 1 KB each) stay in flight
// across the barrier via s_waitcnt vmcnt(4) -> ~4 KB/wave in flight
// (v1's VGPR round-trip staging held only ~64 B/wave -> 2.95 TB/s cap).
// ---------------------------------------------------------------------------
__global__ __launch_bounds__(256) void gemm_stream(
    const ushort_t* __restrict__ adjUb, const ushort_t* __restrict__ adjMb,
    const ushort_t* __restrict__ mT, const ushort_t* __restrict__ uT,
    float* __restrict__ tmp_u, float* __restrict__ tmp_m)
{
    __shared__ ushort_t As[2 * 64 * 64];   // 16 KB
    __shared__ ushort_t Bs[2 * 64 * 64];   // 16 KB

    int bid = blockIdx.x, t = threadIdx.x;
    bool movie = bid < MOVIE_BLOCKS;
    int tt = movie ? bid : bid - MOVIE_BLOCKS;
    int mt = tt / SPLIT, ch = tt - mt * SPLIT;
    int M0 = mt * 64;
    int ldK = movie ? NUQ : NMQ;
    int KC  = movie ? (NUQ / SPLIT) : (NMQ / SPLIT);   // 3200 / 1600
    int K0  = ch * KC;
    const ushort_t* Ab = movie ? adjMb : adjUb;
    const ushort_t* BT = movie ? uT : mT;
    float* outp = movie ? (tmp_m + ((size_t)ch * NMQ + M0) * 64)
                        : (tmp_u + ((size_t)ch * NUQ + M0) * 64);

    int lane = t & 63, w = t >> 6;
    int W16 = w * 16;

    // ---- staging source addresses (per-lane, inverse-swizzled chunk) ----
    int lr = lane >> 3;                 // row within 8-row group
    int lc = (lane & 7) ^ lr;           // source chunk = dest chunk ^ (row&7)
    const ushort_t* aSrc0 = Ab + (size_t)(M0 + W16 + 0 + lr) * ldK + K0 + lc * 8;
    const ushort_t* aSrc1 = Ab + (size_t)(M0 + W16 + 8 + lr) * ldK + K0 + lc * 8;
    const ushort_t* bSrc0 = BT + (size_t)(W16 + 0 + lr) * ldK + K0 + lc * 8;
    const ushort_t* bSrc1 = BT + (size_t)(W16 + 8 + lr) * ldK + K0 + lc * 8;

    // ---- fragment read coords (swizzled) ----
    int mrow = lane & 15, q = lane >> 4;
    int s3 = mrow & 7;
    int cswz = (q ^ s3) * 8;            // chunk base; ks toggles bit2 (q^4ks = q|4ks)

    f32x4 acc[4];
#pragma unroll
    for (int nb = 0; nb < 4; nb++) acc[nb] = (f32x4){0.f, 0.f, 0.f, 0.f};

    int NT = KC >> 6;

#define STAGE_TILE(buf, kofs)                                   \
    do {                                                        \
        ushort_t* ab = As + (buf) * 4096 + W16 * 64;            \
        ushort_t* bb = Bs + (buf) * 4096 + W16 * 64;            \
        glds16(aSrc0 + (kofs), ab);                             \
        glds16(aSrc1 + (kofs), ab + 512);                       \
        glds16(bSrc0 + (kofs), bb);                             \
        glds16(bSrc1 + (kofs), bb + 512);                       \
    } while (0)

    STAGE_TILE(0, 0);

    for (int it = 0; it < NT; ++it) {
        if (it + 1 < NT) {
            STAGE_TILE((it + 1) & 1, (it + 1) * 64);
            asm volatile("s_waitcnt vmcnt(4)" ::: "memory");   // tile `it` done, next in flight
        } else {
            asm volatile("s_waitcnt vmcnt(0)" ::: "memory");
        }
        __builtin_amdgcn_s_barrier();

        const ushort_t* aB = As + (it & 1) * 4096;
        const ushort_t* bB = Bs + (it & 1) * 4096;
#pragma unroll
        for (int ks = 0; ks < 2; ks++) {
            int ck = (cswz ^ (ks * 32));                       // (q^4ks^s3)*8
            short8 a = *(const short8*)(aB + (W16 + mrow) * 64 + ck);
#pragma unroll
            for (int nb = 0; nb < 4; nb++) {
                short8 b = *(const short8*)(bB + (nb * 16 + mrow) * 64 + ck);
                acc[nb] = __builtin_amdgcn_mfma_f32_16x16x32_bf16(a, b, acc[nb], 0, 0, 0);
            }
        }
        asm volatile("" ::: "memory");
        __builtin_amdgcn_s_barrier();   // reads of buf done before next overwrite
    }
#undef STAGE_TILE

    // epilogue: C/D layout col=lane&15, row=quad*4+reg  [m89-verified]
#pragma unroll
    for (int nb = 0; nb < 4; nb++)
#pragma unroll
        for (int r = 0; r < 4; r++)
            outp[(size_t)(W16 + q * 4 + r) * 64 + nb * 16 + mrow] = acc[nb][r];
}

// ---------------------------------------------------------------------------
// Fallback GEMM reading fp32 adj (only if workspace too small for bf16 copy).
// v1 structure: padded LDS, single-buffered.
// ---------------------------------------------------------------------------
__global__ __launch_bounds__(256) void gemm_f32(
    const float* __restrict__ adjU, const float* __restrict__ adjM,
    const ushort_t* __restrict__ mT, const ushort_t* __restrict__ uT,
    float* __restrict__ tmp_u, float* __restrict__ tmp_m)
{
    __shared__ ushort_t Ash[64 * 72];
    __shared__ ushort_t Bsh[64 * 72];

    int bid = blockIdx.x, t = threadIdx.x;
    bool movie = bid < MOVIE_BLOCKS;
    int tt = movie ? bid : bid - MOVIE_BLOCKS;
    int mt = tt / SPLIT, ch = tt - mt * SPLIT;
    int M0 = mt * 64;
    int ldK = movie ? NUQ : NMQ;
    int KC  = movie ? (NUQ / SPLIT) : (NMQ / SPLIT);
    int K0  = ch * KC;
    const float* A = movie ? adjM : adjU;
    const ushort_t* BT = movie ? uT : mT;
    float* outp = movie ? (tmp_m + ((size_t)ch * NMQ + M0) * 64)
                        : (tmp_u + ((size_t)ch * NUQ + M0) * 64);

    int srow = t >> 2;
    int scol = (t & 3) * 16;
    size_t arow = (size_t)(M0 + srow) * ldK;
    size_t brow = (size_t)srow * ldK;

    int lane = t & 63, w = t >> 6;
    int R0 = w * 16, mrow = lane & 15, q = lane >> 4;
    const ushort_t* a_base = &Ash[(R0 + mrow) * 72 + q * 8];
    const ushort_t* b_base = &Bsh[mrow * 72 + q * 8];

    f32x4 acc[4];
#pragma unroll
    for (int nb = 0; nb < 4; nb++) acc[nb] = (f32x4){0.f, 0.f, 0.f, 0.f};

    for (int kk = K0; kk < K0 + KC; kk += 64) {
        const float4* fp = (const float4*)(A + arow + kk + scol);
        float4 f0 = fp[0], f1 = fp[1], f2 = fp[2], f3 = fp[3];
        uint4 q0, q1;
        q0.x = pk_bf16(f0.x, f0.y); q0.y = pk_bf16(f0.z, f0.w);
        q0.z = pk_bf16(f1.x, f1.y); q0.w = pk_bf16(f1.z, f1.w);
        q1.x = pk_bf16(f2.x, f2.y); q1.y = pk_bf16(f2.z, f2.w);
        q1.z = pk_bf16(f3.x, f3.y); q1.w = pk_bf16(f3.z, f3.w);
        *(uint4*)&Ash[srow * 72 + scol] = q0;
        *(uint4*)&Ash[srow * 72 + scol + 8] = q1;
        {
            const uint4* src = (const uint4*)(BT + brow + kk + scol);
            uint4 b0 = src[0], b1 = src[1];
            *(uint4*)&Bsh[srow * 72 + scol] = b0;
            *(uint4*)&Bsh[srow * 72 + scol + 8] = b1;
        }
        __syncthreads();
#pragma unroll
        for (int ks = 0; ks < 2; ks++) {
            short8 a = *(const short8*)(a_base + ks * 32);
#pragma unroll
            for (int nb = 0; nb < 4; nb++) {
                short8 b = *(const short8*)(b_base + nb * 16 * 72 + ks * 32);
                acc[nb] = __builtin_amdgcn_mfma_f32_16x16x32_bf16(a, b, acc[nb], 0, 0, 0);
            }
        }
        __syncthreads();
    }
#pragma unroll
    for (int nb = 0; nb < 4; nb++)
#pragma unroll
        for (int r = 0; r < 4; r++)
            outp[(size_t)(R0 + q * 4 + r) * 64 + nb * 16 + mrow] = acc[nb][r];
}

// ---------------------------------------------------------------------------
// transform: x = sum(5 partials) + prev ; y = lrelu(x @ W.T + 2b)
// writes fp32 table + bf16 transposed table (next GEMM's B^T)
// ---------------------------------------------------------------------------
__global__ __launch_bounds__(256) void transform_kernel(
    const float* __restrict__ tmp_u, const float* __restrict__ tmp_m,
    const float* __restrict__ prev_u, const float* __restrict__ prev_m,
    const float* __restrict__ Wu, const float* __restrict__ bu,
    const float* __restrict__ Wm, const float* __restrict__ bm,
    float* __restrict__ out_u, float* __restrict__ out_m,
    ushort_t* __restrict__ uT, ushort_t* __restrict__ mT)
{
    __shared__ float xs[64 * 65];
    __shared__ float Ws[64 * 65];
    __shared__ float ys[64 * 65];
    int bid = blockIdx.x, t = threadIdx.x;
    bool mside = bid >= 250;
    int row0 = (mside ? (bid - 250) : bid) * 64;
    int Nrows = mside ? NMQ : NUQ;
    const float* tmp  = mside ? tmp_m : tmp_u;
    const float* prev = mside ? prev_m : prev_u;
    const float* W    = mside ? Wm : Wu;
    const float* bias = mside ? bm : bu;
    float* outp   = mside ? out_m : out_u;
    ushort_t* outT = mside ? mT : uT;

    for (int j = 0; j < 16; j++) {
        int idx = j * 256 + t;
        int r = idx >> 6, e = idx & 63;
        size_t g = (size_t)(row0 + r) * 64 + e;
        float v = prev[g];
#pragma unroll
        for (int s = 0; s < SPLIT; s++) v += tmp[(size_t)s * Nrows * 64 + g];
        xs[r * 65 + e] = v;
        Ws[r * 65 + e] = W[idx];    // W[e'][e], e'=r
    }
    __syncthreads();

    int ep = t & 63, rb = t >> 6;
    float acc[16];
    float b2 = 2.0f * bias[ep];
#pragma unroll
    for (int j = 0; j < 16; j++) acc[j] = b2;
    for (int e = 0; e < 64; e++) {
        float w = Ws[ep * 65 + e];
#pragma unroll
        for (int j = 0; j < 16; j++) acc[j] += xs[(j * 4 + rb) * 65 + e] * w;
    }
#pragma unroll
    for (int j = 0; j < 16; j++) {
        float v = acc[j];
        v = v > 0.f ? v : 0.01f * v;        // leaky_relu 0.01
        ys[(j * 4 + rb) * 65 + ep] = v;
    }
    __syncthreads();

    for (int j = 0; j < 16; j++) {
        int idx = j * 256 + t;
        int r = idx >> 6, e = idx & 63;
        outp[(size_t)(row0 + r) * 64 + e] = ys[r * 65 + e];
        int e2 = r, rr = e;
        outT[(size_t)e2 * Nrows + row0 + rr] = (ushort_t)bf16_bits(ys[rr * 65 + e2]);
    }
}

// ---------------------------------------------------------------------------
// gather: out[b] = sum_l sum_e u_l[uid[b]][e]*m_l[mid[b]][e]*Wo[l*64+e] + bo
// ---------------------------------------------------------------------------
__global__ __launch_bounds__(256) void gather_kernel(
    const float* __restrict__ u0, const float* __restrict__ u1,
    const float* __restrict__ u2, const float* __restrict__ u3,
    const float* __restrict__ m0, const float* __restrict__ m1,
    const float* __restrict__ m2, const float* __restrict__ m3,
    const float* __restrict__ Wo, const float* __restrict__ bo,
    const int* __restrict__ uid, const int* __restrict__ mid,
    float* __restrict__ out)
{
    int t = threadIdx.x;
    int lane = t & 63, wv = t >> 6;
    int b = blockIdx.x * 4 + wv;            // grid = 25000 -> exact B
    size_t ui = (size_t)uid[b] * 64 + lane;
    size_t mi = (size_t)mid[b] * 64 + lane;
    float acc = u0[ui] * m0[mi] * Wo[lane]
              + u1[ui] * m1[mi] * Wo[64 + lane]
              + u2[ui] * m2[mi] * Wo[128 + lane]
              + u3[ui] * m3[mi] * Wo[192 + lane];
#pragma unroll
    for (int off = 32; off >= 1; off >>= 1) acc += __shfl_xor(acc, off, 64);
    if (lane == 0) out[b] = acc + bo[0];
}

// ---------------------------------------------------------------------------
extern "C" void kernel_launch(void* const* d_in, const int* in_sizes, int n_in,
                              void* d_out, int out_size, void* d_ws, size_t ws_size,
                              hipStream_t stream)
{
    const float* adjU = (const float*)d_in[0];
    const float* adjM = (const float*)d_in[1];
    const float* uemb = (const float*)d_in[2];
    const float* memb = (const float*)d_in[3];
    const float* Wu   = (const float*)d_in[4];
    const float* bu   = (const float*)d_in[5];
    const float* Wm   = (const float*)d_in[6];
    const float* bm   = (const float*)d_in[7];
    const float* Wo   = (const float*)d_in[8];
    const float* bo   = (const float*)d_in[9];
    const int* uid    = (const int*)d_in[10];
    const int* mid    = (const int*)d_in[11];
    float* out = (float*)d_out;

    char* ws = (char*)d_ws;
    size_t off = 0;
    auto alloc = [&](size_t bytes) -> void* {
        void* p = ws + off;
        off += (bytes + 255) & ~(size_t)255;
        return p;
    };
    float* u_ws = (float*)alloc((size_t)3 * NUQ * 64 * 4);   // u1,u2,u3
    float* m_ws = (float*)alloc((size_t)3 * NMQ * 64 * 4);   // m1,m2,m3
    ushort_t* uT = (ushort_t*)alloc((size_t)64 * NUQ * 2);   // current layer u^T bf16
    ushort_t* mT = (ushort_t*)alloc((size_t)64 * NMQ * 2);
    float* tmp_u = (float*)alloc((size_t)SPLIT * NUQ * 64 * 4);
    float* tmp_m = (float*)alloc((size_t)SPLIT * NMQ * 64 * 4);
    ushort_t* adjUb = (ushort_t*)alloc((size_t)NUQ * NMQ * 2);
    ushort_t* adjMb = (ushort_t*)alloc((size_t)NMQ * NUQ * 2);
    bool compress = (ws_size >= off);

    prep_kernel<<<375, 256, 0, stream>>>(uemb, memb, uT, mT);
    if (compress) {
        convert_kernel<<<2048, 256, 0, stream>>>(adjU, adjUb, (long)NUQ * NMQ);
        convert_kernel<<<2048, 256, 0, stream>>>(adjM, adjMb, (long)NMQ * NUQ);
    }

    for (int l = 0; l < LQ; l++) {
        if (compress)
            gemm_stream<<<GEMM_BLOCKS, 256, 0, stream>>>(adjUb, adjMb, mT, uT, tmp_u, tmp_m);
        else
            gemm_f32<<<GEMM_BLOCKS, 256, 0, stream>>>(adjU, adjM, mT, uT, tmp_u, tmp_m);
        const float* pu = (l == 0) ? uemb : (u_ws + (size_t)(l - 1) * NUQ * 64);
        const float* pm = (l == 0) ? memb : (m_ws + (size_t)(l - 1) * NMQ * 64);
        transform_kernel<<<375, 256, 0, stream>>>(
            tmp_u, tmp_m, pu, pm,
            Wu + (size_t)l * 64 * 64, bu + (size_t)l * 64,
            Wm + (size_t)l * 64 * 64, bm + (size_t)l * 64,
            u_ws + (size_t)l * NUQ * 64, m_ws + (size_t)l * NMQ * 64,
            uT, mT);
    }

    gather_kernel<<<BQ / 4, 256, 0, stream>>>(
        uemb, u_ws, u_ws + (size_t)NUQ * 64, u_ws + (size_t)2 * NUQ * 64,
        memb, m_ws, m_ws + (size_t)NMQ * 64, m_ws + (size_t)2 * NMQ * 64,
        Wo, bo, uid, mid, out);
}